// Round 2
// baseline (35.368 us; speedup 1.0000x reference)
//
#include <hip/hip_runtime.h>
#include <math.h>

#define MU 1e-4f
#define COUNT_EPS 1e-4f
#define TWO_PI_F 6.2831853071795864769f

constexpr int P = 8;    // partitions (reference fixes 8)
constexpr int N = 128;  // neighbors
constexpr int RPB = 2;  // rows (batch elements) per block

__global__ __launch_bounds__(256) void social_circle_kernel(
    const float* __restrict__ trajs,   // [B, 8, 2]
    const float* __restrict__ nei,     // [B, 128, 8, 2]
    float* __restrict__ social,        // [B, P, 3]
    float* __restrict__ fdir)          // [B, N]
{
    const int tid = threadIdx.x;
    const int r   = tid >> 7;         // row within block
    const int n   = tid & (N - 1);    // neighbor index
    const int w   = (tid >> 6) & 1;   // wave within row
    const size_t b = (size_t)blockIdx.x * RPB + r;

    // per-row, per-wave accumulators: {sum_speed, sum_dist, sum_dir, count}
    __shared__ float acc[RPB][2][P][4];
    if (tid < RPB * 2 * P * 4) ((float*)acc)[tid] = 0.0f;

    // ---- issue the 64B/lane nei loads first (4x dwordx4 in flight) ----
    const float4* np4 = (const float4*)(nei + (b * N + n) * 16);
    const float4 v0 = np4[0], v1 = np4[1], v2 = np4[2], v3 = np4[3];

    // ---- trajs: wave-uniform addresses -> scalar loads, no barrier ----
    const float* tb = trajs + b * 16;
    const float fx0 = tb[0],  fy0 = tb[1];   // t=0
    const float lx  = tb[14], ly  = tb[15];  // t=7
    const float ox = lx - fx0, oy = ly - fy0;
    const float obs_len = sqrtf(ox * ox + oy * oy);

    // validity mask: sum over all 16 values != 0
    const float msum = v0.x + v0.y + v0.z + v0.w
                     + v1.x + v1.y + v1.z + v1.w
                     + v2.x + v2.y + v2.z + v2.w
                     + v3.x + v3.y + v3.z + v3.w;

    const float ex = v3.z, ey = v3.w;            // t=7
    const float nvx = ex - v0.x, nvy = ey - v0.y;
    const float nei_len = sqrtf(nvx * nvx + nvy * nvy);
    const float f_speed = (nei_len + MU) / (obs_len + MU);

    const float px = ex - lx, py = ey - ly;
    const float f_dist = sqrtf(px * px + py * py);

    float d = atan2f(py, px);
    if (d < 0.0f) d += TWO_PI_F;   // == jnp.mod(atan2, 2*pi) on [-pi,pi]

    fdir[b * N + n] = d;

    // same float32 division as reference; idx==P (d rounding to 2*pi)
    // matches one_hot out-of-range: excluded.
    const int idx = (int)(d / (TWO_PI_F / P));

    __syncthreads();  // acc init visible

    if ((msum != 0.0f) && (idx >= 0) && (idx < P)) {
        float* a = &acc[r][w][idx][0];   // 32 addrs/wave -> 1 per bank
        atomicAdd(a + 0, f_speed);
        atomicAdd(a + 1, f_dist);
        atomicAdd(a + 2, d);
        atomicAdd(a + 3, 1.0f);
    }
    __syncthreads();

    if (tid < RPB * P * 3) {
        const int rr = tid / (P * 3);
        const int wi = tid % (P * 3);
        const int p = wi / 3, f = wi % 3;
        const float s = acc[rr][0][p][f] + acc[rr][1][p][f];
        const float c = acc[rr][0][p][3] + acc[rr][1][p][3];
        social[((size_t)blockIdx.x * RPB + rr) * (P * 3) + wi] = s / (c + COUNT_EPS);
    }
}

extern "C" void kernel_launch(void* const* d_in, const int* in_sizes, int n_in,
                              void* d_out, int out_size, void* d_ws, size_t ws_size,
                              hipStream_t stream) {
    const float* trajs = (const float*)d_in[0];
    const float* nei   = (const float*)d_in[1];
    const int B = in_sizes[0] / 16;  // trajs is [B, 8, 2]

    float* social = (float*)d_out;                       // [B, 8, 3]
    float* fdir   = (float*)d_out + (size_t)B * P * 3;   // [B, 128]

    social_circle_kernel<<<B / RPB, 256, 0, stream>>>(trajs, nei, social, fdir);
}

// Round 3
// 31.579 us; speedup vs baseline: 1.1200x; 1.1200x over previous
//
#include <hip/hip_runtime.h>
#include <math.h>

#define MU 1e-4f
#define COUNT_EPS 1e-4f
#define TWO_PI_F 6.2831853071795864769f

constexpr int P = 8;    // partitions (reference fixes 8)
constexpr int N = 128;  // neighbors
constexpr int WPB = 4;  // waves per block (256 threads)
constexpr int RPW = 2;  // rows per wave (grid-stride, no barriers between)

__global__ __launch_bounds__(256) void social_circle_kernel(
    const float* __restrict__ trajs,   // [B, 8, 2]
    const float* __restrict__ nei,     // [B, 128, 8, 2]
    float* __restrict__ social,        // [B, P, 3]
    float* __restrict__ fdir,          // [B, N]
    int B)
{
    const int lane = threadIdx.x & 63;
    const int wib  = threadIdx.x >> 6;
    const int wave = blockIdx.x * WPB + wib;

    // per-WAVE accumulator: no cross-wave sharing -> no __syncthreads ever
    __shared__ float accs[WPB][P * 4];   // {speed, dist, dir, count} x 8 buckets
    float* acc = accs[wib];

    for (int i = 0; i < RPW; ++i) {
        const size_t b = (size_t)wave * RPW + i;
        if (b >= (size_t)B) break;

        // zero this wave's buckets (lanes 0..31); DS pipe is in-order per wave,
        // so this is complete before this wave's ds_add atomics below.
        if (lane < P * 4) acc[lane] = 0.0f;

        // trajs row (wave-uniform address -> broadcast load)
        const float* tb = trajs + b * 16;
        const float fx0 = tb[0],  fy0 = tb[1];
        const float lx  = tb[14], ly  = tb[15];
        const float ox = lx - fx0, oy = ly - fy0;
        const float obs_len = sqrtf(ox * ox + oy * oy);

        const float4* base = (const float4*)(nei + b * (size_t)N * 16);

        float dval[2], spd[2], dst[2];
        int   idx[2];
        bool  val[2];

        #pragma unroll
        for (int h = 0; h < 2; ++h) {
            const int n = lane + 64 * h;
            const float4 v0 = base[n * 4 + 0];
            const float4 v1 = base[n * 4 + 1];
            const float4 v2 = base[n * 4 + 2];
            const float4 v3 = base[n * 4 + 3];

            const float msum = v0.x + v0.y + v0.z + v0.w
                             + v1.x + v1.y + v1.z + v1.w
                             + v2.x + v2.y + v2.z + v2.w
                             + v3.x + v3.y + v3.z + v3.w;

            const float ex = v3.z, ey = v3.w;          // t=7
            const float nvx = ex - v0.x, nvy = ey - v0.y;
            const float nl = sqrtf(nvx * nvx + nvy * nvy);
            spd[h] = (nl + MU) / (obs_len + MU);

            const float px = ex - lx, py = ey - ly;
            dst[h] = sqrtf(px * px + py * py);

            float d = atan2f(py, px);
            if (d < 0.0f) d += TWO_PI_F;   // == jnp.mod(atan2, 2pi) on [-pi,pi]
            dval[h] = d;

            idx[h] = (int)(d / (TWO_PI_F / P));
            // idx==P (d rounded up to 2pi) matches one_hot out-of-range: excluded
            val[h] = (msum != 0.0f) && (idx[h] >= 0) && (idx[h] < P);
        }

        #pragma unroll
        for (int h = 0; h < 2; ++h) {
            if (val[h]) {
                float* ap = &acc[idx[h] * 4];
                atomicAdd(ap + 0, spd[h]);
                atomicAdd(ap + 1, dst[h]);
                atomicAdd(ap + 2, dval[h]);
                atomicAdd(ap + 3, 1.0f);
            }
        }

        // coalesced fdir stores (two contiguous 256B wave stores)
        fdir[b * N + lane]      = dval[0];
        fdir[b * N + 64 + lane] = dval[1];

        // drain this wave's ds_adds before reading buckets (wave-internal, no barrier)
        asm volatile("s_waitcnt lgkmcnt(0)" ::: "memory");

        if (lane < P * 3) {
            const int p = lane / 3, f = lane % 3;
            social[b * (P * 3) + lane] = acc[p * 4 + f] / (acc[p * 4 + 3] + COUNT_EPS);
        }
    }
}

extern "C" void kernel_launch(void* const* d_in, const int* in_sizes, int n_in,
                              void* d_out, int out_size, void* d_ws, size_t ws_size,
                              hipStream_t stream) {
    const float* trajs = (const float*)d_in[0];
    const float* nei   = (const float*)d_in[1];
    const int B = in_sizes[0] / 16;  // trajs is [B, 8, 2]

    float* social = (float*)d_out;                       // [B, 8, 3]
    float* fdir   = (float*)d_out + (size_t)B * P * 3;   // [B, 128]

    const int waves  = (B + RPW - 1) / RPW;
    const int blocks = (waves + WPB - 1) / WPB;
    social_circle_kernel<<<blocks, WPB * 64, 0, stream>>>(trajs, nei, social, fdir, B);
}